// Round 1
// baseline (43.358 us; speedup 1.0000x reference)
//
#include <hip/hip_runtime.h>
#include <stdint.h>

// SWF2LUT 4-simplex interpolation, mode 's'.
// img_in: (8,1,513,513) f32, integer values 0..255
// weight: (17^4, 3) f32  -> quantized clip(round(w*127),-127,127)
// out:    (8,1,512,512,3) f32

#define LQ   17
#define L2C  (17 * 17)        // 289
#define L3C  (17 * 17 * 17)   // 4913
#define NENT (L3C * 17)       // 83521
#define SUMSTRIDE (L3C + L2C + LQ + 1)  // 5220 (constant last cumsum)

// ---- pre-kernel: quantize weight table and pack 3x int8 into one u32 ----
__global__ __launch_bounds__(256) void quant_pack_kernel(
    const float* __restrict__ w, uint32_t* __restrict__ tab, int n) {
    int e = blockIdx.x * 256 + threadIdx.x;
    if (e >= n) return;
    int q0 = (int)rintf(w[e * 3 + 0] * 127.0f);
    int q1 = (int)rintf(w[e * 3 + 1] * 127.0f);
    int q2 = (int)rintf(w[e * 3 + 2] * 127.0f);
    q0 = min(127, max(-127, q0));
    q1 = min(127, max(-127, q1));
    q2 = min(127, max(-127, q2));
    tab[e] = (uint32_t)(q0 & 0xFF) | ((uint32_t)(q1 & 0xFF) << 8) |
             ((uint32_t)(q2 & 0xFF) << 16);
}

__device__ __forceinline__ int stride_of(int j) {
    // strides[j] = 17^(3-j); cndmask chain, no runtime-indexed array
    return j == 0 ? L3C : (j == 1 ? L2C : (j == 2 ? LQ : 1));
}

// ---- main kernel (packed int8 table in d_ws) ----
// One thread = 4 consecutive x pixels. 8*512*128 = 524288 threads.
__global__ __launch_bounds__(256) void interp_packed_kernel(
    const float* __restrict__ img, const uint32_t* __restrict__ tab,
    float* __restrict__ out) {
    int gid = blockIdx.x * 256 + threadIdx.x;   // 0..524287
    int x0 = (gid & 127) << 2;                  // 0..508 step 4
    int y  = (gid >> 7) & 511;
    int im = gid >> 16;                         // 0..7

    const float* r0 = img + im * (513 * 513) + y * 513 + x0;
    const float* r1 = r0 + 513;
    float v0[5], v1[5];
#pragma unroll
    for (int i = 0; i < 5; ++i) { v0[i] = r0[i]; v1[i] = r1[i]; }

    float res[12];
#pragma unroll
    for (int i = 0; i < 4; ++i) {
        int a = (int)v0[i], b = (int)v0[i + 1];
        int c = (int)v1[i], d = (int)v1[i + 1];
        int base = (a >> 4) * L3C + (b >> 4) * L2C + (c >> 4) * LQ + (d >> 4);
        // keys: f*4 + coord_index  (distinct; replicates argsort(-tie_key))
        int k0 = ((a & 15) << 2) | 0;
        int k1 = ((b & 15) << 2) | 1;
        int k2 = ((c & 15) << 2) | 2;
        int k3 = ((d & 15) << 2) | 3;
        int t;
        if (k0 < k1) { t = k0; k0 = k1; k1 = t; }
        if (k2 < k3) { t = k2; k2 = k3; k3 = t; }
        if (k0 < k2) { t = k0; k0 = k2; k2 = t; }
        if (k1 < k3) { t = k1; k1 = k3; k3 = t; }
        if (k1 < k2) { t = k1; k1 = k2; k2 = t; }
        int fs0 = k0 >> 2, fs1 = k1 >> 2, fs2 = k2 >> 2, fs3 = k3 >> 2;
        int s0 = stride_of(k0 & 3);
        int s1 = stride_of(k1 & 3);
        int s2 = stride_of(k2 & 3);
        int i0 = base;
        int i1 = base + s0;
        int i2 = i1 + s1;
        int i3 = i2 + s2;
        int i4 = base + SUMSTRIDE;   // cumsum of all 4 strides is constant
        uint32_t u0 = tab[i0], u1 = tab[i1], u2 = tab[i2], u3 = tab[i3],
                 u4 = tab[i4];
        int w0 = 16 - fs0, w1 = fs0 - fs1, w2 = fs1 - fs2, w3 = fs2 - fs3,
            w4 = fs3;
#pragma unroll
        for (int ch = 0; ch < 3; ++ch) {
            int sh = 24 - ch * 8;
            int p0 = (int)(u0 << sh) >> 24;
            int p1 = (int)(u1 << sh) >> 24;
            int p2 = (int)(u2 << sh) >> 24;
            int p3 = (int)(u3 << sh) >> 24;
            int p4 = (int)(u4 << sh) >> 24;
            int acc = w0 * p0 + w1 * p1 + w2 * p2 + w3 * p3 + w4 * p4;
            res[i * 3 + ch] = (float)acc * 0.0625f;  // /16 exact
        }
    }

    int opix = ((im * 512 + y) * 512 + x0) * 3;  // multiple of 12 -> 48B aligned
    float4* o = (float4*)(out + opix);
    o[0] = make_float4(res[0], res[1], res[2], res[3]);
    o[1] = make_float4(res[4], res[5], res[6], res[7]);
    o[2] = make_float4(res[8], res[9], res[10], res[11]);
}

// ---- fallback: gather f32 weights, quantize inline (if ws too small) ----
__device__ __forceinline__ float quant1(float x) {
    return fminf(127.0f, fmaxf(-127.0f, rintf(x * 127.0f)));
}

__global__ __launch_bounds__(256) void interp_float_kernel(
    const float* __restrict__ img, const float* __restrict__ wgt,
    float* __restrict__ out) {
    int gid = blockIdx.x * 256 + threadIdx.x;
    int x0 = (gid & 127) << 2;
    int y  = (gid >> 7) & 511;
    int im = gid >> 16;

    const float* r0 = img + im * (513 * 513) + y * 513 + x0;
    const float* r1 = r0 + 513;
    float v0[5], v1[5];
#pragma unroll
    for (int i = 0; i < 5; ++i) { v0[i] = r0[i]; v1[i] = r1[i]; }

    float res[12];
#pragma unroll
    for (int i = 0; i < 4; ++i) {
        int a = (int)v0[i], b = (int)v0[i + 1];
        int c = (int)v1[i], d = (int)v1[i + 1];
        int base = (a >> 4) * L3C + (b >> 4) * L2C + (c >> 4) * LQ + (d >> 4);
        int k0 = ((a & 15) << 2) | 0;
        int k1 = ((b & 15) << 2) | 1;
        int k2 = ((c & 15) << 2) | 2;
        int k3 = ((d & 15) << 2) | 3;
        int t;
        if (k0 < k1) { t = k0; k0 = k1; k1 = t; }
        if (k2 < k3) { t = k2; k2 = k3; k3 = t; }
        if (k0 < k2) { t = k0; k0 = k2; k2 = t; }
        if (k1 < k3) { t = k1; k1 = k3; k3 = t; }
        if (k1 < k2) { t = k1; k1 = k2; k2 = t; }
        int fs0 = k0 >> 2, fs1 = k1 >> 2, fs2 = k2 >> 2, fs3 = k3 >> 2;
        int s0 = stride_of(k0 & 3);
        int s1 = stride_of(k1 & 3);
        int s2 = stride_of(k2 & 3);
        int i0 = base;
        int i1 = base + s0;
        int i2 = i1 + s1;
        int i3 = i2 + s2;
        int i4 = base + SUMSTRIDE;
        float w0 = (float)(16 - fs0), w1 = (float)(fs0 - fs1),
              w2 = (float)(fs1 - fs2), w3 = (float)(fs2 - fs3),
              w4 = (float)fs3;
#pragma unroll
        for (int ch = 0; ch < 3; ++ch) {
            float p0 = quant1(wgt[i0 * 3 + ch]);
            float p1 = quant1(wgt[i1 * 3 + ch]);
            float p2 = quant1(wgt[i2 * 3 + ch]);
            float p3 = quant1(wgt[i3 * 3 + ch]);
            float p4 = quant1(wgt[i4 * 3 + ch]);
            float acc = w0 * p0 + w1 * p1 + w2 * p2 + w3 * p3 + w4 * p4;
            res[i * 3 + ch] = acc * 0.0625f;
        }
    }

    int opix = ((im * 512 + y) * 512 + x0) * 3;
    float4* o = (float4*)(out + opix);
    o[0] = make_float4(res[0], res[1], res[2], res[3]);
    o[1] = make_float4(res[4], res[5], res[6], res[7]);
    o[2] = make_float4(res[8], res[9], res[10], res[11]);
}

extern "C" void kernel_launch(void* const* d_in, const int* in_sizes, int n_in,
                              void* d_out, int out_size, void* d_ws,
                              size_t ws_size, hipStream_t stream) {
    const float* img = (const float*)d_in[0];
    const float* wgt = (const float*)d_in[1];
    float* out = (float*)d_out;

    const int n_groups = 8 * 512 * 128;      // 524288 threads, 4 px each
    const int grid = n_groups / 256;         // 2048 blocks

    if (ws_size >= (size_t)NENT * sizeof(uint32_t) && d_ws != nullptr) {
        uint32_t* tab = (uint32_t*)d_ws;
        quant_pack_kernel<<<(NENT + 255) / 256, 256, 0, stream>>>(wgt, tab,
                                                                  NENT);
        interp_packed_kernel<<<grid, 256, 0, stream>>>(img, tab, out);
    } else {
        interp_float_kernel<<<grid, 256, 0, stream>>>(img, wgt, out);
    }
}